// Round 5
// baseline (57.962 us; speedup 1.0000x reference)
//
#include <hip/hip_runtime.h>
#include <hip/hip_bf16.h>
#include <stdint.h>

#define NN 4096
#define DD 1024
#define INV_T 10.0f

typedef float f32x4 __attribute__((ext_vector_type(4)));
typedef __bf16 bf16x8 __attribute__((ext_vector_type(8)));

__device__ __forceinline__ unsigned short f2bf(float x) {
  return __builtin_bit_cast(unsigned short, __float2bfloat16(x));
}

__device__ __forceinline__ void gload_lds16(const void* g, void* l) {
  __builtin_amdgcn_global_load_lds(
      (const __attribute__((address_space(1))) void*)g,
      (__attribute__((address_space(3))) void*)l, 16, 0, 0);
}

// ---------- kernel 1: row-L2-normalize -> bf16, exact fp32 diagonal, zero sums ----------
__global__ __launch_bounds__(256) void nrm_kernel(
    const float* __restrict__ e1, const float* __restrict__ e2,
    unsigned short* __restrict__ e1n, unsigned short* __restrict__ e2n,
    float* __restrict__ log_diag, float* __restrict__ exp_diag,
    float* __restrict__ row_sum, float* __restrict__ col_sum)
{
  const int row  = blockIdx.x;
  const int tid  = threadIdx.x;
  const int lane = tid & 63;
  const int wave = tid >> 6;
  const int64_t base = (int64_t)row * DD;

  const float4 v1 = *reinterpret_cast<const float4*>(e1 + base + tid * 4);
  const float4 v2 = *reinterpret_cast<const float4*>(e2 + base + tid * 4);

  float ss1 = v1.x*v1.x + v1.y*v1.y + v1.z*v1.z + v1.w*v1.w;
  float ss2 = v2.x*v2.x + v2.y*v2.y + v2.z*v2.z + v2.w*v2.w;
  float d12 = v1.x*v2.x + v1.y*v2.y + v1.z*v2.z + v1.w*v2.w;

  #pragma unroll
  for (int off = 1; off < 64; off <<= 1) {
    ss1 += __shfl_xor(ss1, off);
    ss2 += __shfl_xor(ss2, off);
    d12 += __shfl_xor(d12, off);
  }

  __shared__ float red[3][4];
  if (lane == 0) { red[0][wave] = ss1; red[1][wave] = ss2; red[2][wave] = d12; }
  __syncthreads();
  ss1 = red[0][0] + red[0][1] + red[0][2] + red[0][3];
  ss2 = red[1][0] + red[1][1] + red[1][2] + red[1][3];
  d12 = red[2][0] + red[2][1] + red[2][2] + red[2][3];

  const float inv1 = 1.0f / fmaxf(sqrtf(ss1), 1e-12f);
  const float inv2 = 1.0f / fmaxf(sqrtf(ss2), 1e-12f);

  if (tid == 0) {
    const float ld = d12 * inv1 * inv2 * INV_T;
    log_diag[row] = ld;
    exp_diag[row] = __expf(ld);
    row_sum[row] = 0.0f;          // replaces the memset dispatch
    col_sum[row] = 0.0f;
  }

  ushort4 o1, o2;
  o1.x = f2bf(v1.x * inv1); o1.y = f2bf(v1.y * inv1);
  o1.z = f2bf(v1.z * inv1); o1.w = f2bf(v1.w * inv1);
  o2.x = f2bf(v2.x * inv2); o2.y = f2bf(v2.y * inv2);
  o2.z = f2bf(v2.z * inv2); o2.w = f2bf(v2.w * inv2);
  *reinterpret_cast<ushort4*>(e1n + base + tid * 4) = o1;
  *reinterpret_cast<ushort4*>(e2n + base + tid * 4) = o2;
}

// stage one k-half (256 rows x 32 cols) into LDS, linear dest, XOR-swizzled source.
// phys[row][s] = G[row][ s ^ ((row>>1)&3) ]  (16B slots). lane l: row = r0+(l>>2),
// slot = l&3  ->  source slot = (l&3) ^ ((l>>3)&3).
__device__ __forceinline__ void stage_khalf(
    const unsigned short* __restrict__ src, int row_base, int kcol,
    unsigned short (*dst)[32], int wave, int lane)
{
  const int r0 = wave * 16 + (lane >> 2);
  const int c  = ((lane & 3) ^ ((lane >> 3) & 3)) * 8;
  gload_lds16(src + (int64_t)(row_base + r0) * DD + kcol + c,
              &dst[wave * 16][0]);
  gload_lds16(src + (int64_t)(row_base + 128 + r0) * DD + kcol + c,
              &dst[128 + wave * 16][0]);
}

// ---------- kernel 2: fused 256x256 GEMM, register-pipelined 32-phase schedule ----------
// 8 waves (2M x 4N). Phase = one k-half (32 cols). LDS [tilebuf][kk][256][32],
// XOR bank swizzle (conflict-free, verified R4). Register pipeline: B-frags
// double-buffered (read for p+1 during p); A-frags guarded by counted lgkmcnt
// so the second 16-MFMA subcluster covers their latency. vmcnt(4) steady,
// staging distance 3 phases. Fully unrolled: all offsets/waits are immediates.
__global__ __launch_bounds__(512, 2) void gemm_kernel(
    const unsigned short* __restrict__ A,   // e1n [NN][DD] bf16 bits
    const unsigned short* __restrict__ B,   // e2n [NN][DD] bf16 bits
    float* __restrict__ row_sum, float* __restrict__ col_sum)
{
  __shared__ __align__(16) unsigned short lds_a[2][2][256][32];  // 64 KiB
  __shared__ __align__(16) unsigned short lds_b[2][2][256][32];  // 64 KiB

  const int tid  = threadIdx.x;
  const int lane = tid & 63;
  const int wave = tid >> 6;          // 0..7
  const int wm = wave >> 2;           // 0..1 : rows [wm*128, +128)
  const int wn = wave & 3;            // 0..3 : cols [wn*64, +64)

  // XCD-aware block swizzle: each XCD owns a 4x8 rectangle of the 16x16 grid
  const int bid = blockIdx.x;
  const int xcd = bid & 7;
  const int k   = bid >> 3;           // 0..31 within XCD
  const int brow = ((xcd >> 1) * 4 + (k >> 3)) * 256;
  const int bcol = ((xcd & 1) * 8 + (k & 7)) * 256;

  const int fr = lane & 15;
  const int fq = lane >> 4;
  const int rslot = (fq ^ ((fr >> 1) & 3)) * 8;   // swizzled read col (elems)

  f32x4 acc[8][4] = {};
  bf16x8 bv[2][4];   // double-buffered B fragments (indexed by p&1, unrolled->static)

  // ---- prologue: stage phases 0,1,2 (k-halves), preload bv for phase 0 ----
  stage_khalf(A, brow, 0,  lds_a[0][0], wave, lane);
  stage_khalf(B, bcol, 0,  lds_b[0][0], wave, lane);
  stage_khalf(A, brow, 32, lds_a[0][1], wave, lane);
  stage_khalf(B, bcol, 32, lds_b[0][1], wave, lane);
  stage_khalf(A, brow, 64, lds_a[1][0], wave, lane);
  stage_khalf(B, bcol, 64, lds_b[1][0], wave, lane);
  asm volatile("s_waitcnt vmcnt(8)" ::: "memory");   // phase-0 slot landed
  __builtin_amdgcn_s_barrier();
  #pragma unroll
  for (int j = 0; j < 4; ++j)
    bv[0][j] = *reinterpret_cast<const bf16x8*>(
        &lds_b[0][0][wn * 64 + j * 16 + fr][rslot]);

  #pragma unroll
  for (int p = 0; p < 32; ++p) {
    const int t   = p >> 1,  kk  = p & 1,  c  = t & 1;
    const int pn  = p + 1;
    const int tn  = pn >> 1, kkn = pn & 1, cn = tn & 1;
    const int cur = p & 1,   nxt = pn & 1;

    // slot for phase p+1 was staged 3 phases ago; 4 newer gloads may fly
    if (p <= 29)      asm volatile("s_waitcnt vmcnt(4)" ::: "memory");
    else if (p == 30) asm volatile("s_waitcnt vmcnt(0)" ::: "memory");
    __builtin_amdgcn_s_barrier();

    // A fragments for THIS phase (a0 first, then a1 - wait counts rely on order)
    bf16x8 a0[4], a1[4];
    #pragma unroll
    for (int i = 0; i < 4; ++i)
      a0[i] = *reinterpret_cast<const bf16x8*>(
          &lds_a[c][kk][wm * 128 + i * 16 + fr][rslot]);
    #pragma unroll
    for (int i = 0; i < 4; ++i)
      a1[i] = *reinterpret_cast<const bf16x8*>(
          &lds_a[c][kk][wm * 128 + 64 + i * 16 + fr][rslot]);
    // B fragments for NEXT phase (stay in flight across the whole MFMA body)
    if (p <= 30) {
      #pragma unroll
      for (int j = 0; j < 4; ++j)
        bv[nxt][j] = *reinterpret_cast<const bf16x8*>(
            &lds_b[cn][kkn][wn * 64 + j * 16 + fr][rslot]);
    }
    // stage the k-half for phase p+3
    if (p <= 28) {
      const int ps = p + 3, ts = ps >> 1, ks = ps & 1;
      stage_khalf(A, brow, ts * 64 + ks * 32, lds_a[ts & 1][ks], wave, lane);
      stage_khalf(B, bcol, ts * 64 + ks * 32, lds_b[ts & 1][ks], wave, lane);
    }

    // wait a0 only (a1 + bvNext remain outstanding)
    if (p <= 30) asm volatile("s_waitcnt lgkmcnt(8)" ::: "memory");
    else         asm volatile("s_waitcnt lgkmcnt(4)" ::: "memory");
    __builtin_amdgcn_sched_barrier(0);
    __builtin_amdgcn_s_setprio(1);
    #pragma unroll
    for (int i = 0; i < 4; ++i) {
      #pragma unroll
      for (int j = 0; j < 4; ++j)
        acc[i][j] = __builtin_amdgcn_mfma_f32_16x16x32_bf16(
            a0[i], bv[cur][j], acc[i][j], 0, 0, 0);
    }
    // wait a1 (bvNext remains outstanding into the next phase)
    if (p <= 30) asm volatile("s_waitcnt lgkmcnt(4)" ::: "memory");
    else         asm volatile("s_waitcnt lgkmcnt(0)" ::: "memory");
    __builtin_amdgcn_sched_barrier(0);
    #pragma unroll
    for (int i = 0; i < 4; ++i) {
      #pragma unroll
      for (int j = 0; j < 4; ++j)
        acc[4 + i][j] = __builtin_amdgcn_mfma_f32_16x16x32_bf16(
            a1[i], bv[cur][j], acc[4 + i][j], 0, 0, 0);
    }
    __builtin_amdgcn_s_setprio(0);
  }

  // ---- fused epilogue: v = exp(10*dot); row & col partial sums ----
  // C/D layout: col = fr, row = fq*4 + j (within each 16x16 fragment)
  float rowp[8][4];
  float colp[4];
  #pragma unroll
  for (int mi = 0; mi < 8; ++mi)
    #pragma unroll
    for (int j = 0; j < 4; ++j) rowp[mi][j] = 0.0f;
  #pragma unroll
  for (int ni = 0; ni < 4; ++ni) colp[ni] = 0.0f;

  #pragma unroll
  for (int mi = 0; mi < 8; ++mi) {
    #pragma unroll
    for (int ni = 0; ni < 4; ++ni) {
      #pragma unroll
      for (int j = 0; j < 4; ++j) {
        const float v = __expf(acc[mi][ni][j] * INV_T);
        rowp[mi][j] += v;
        colp[ni]    += v;
      }
    }
  }

  // row sums: reduce across 16 col-lanes, 1 atomic per row per wave
  #pragma unroll
  for (int mi = 0; mi < 8; ++mi) {
    #pragma unroll
    for (int j = 0; j < 4; ++j) {
      float r = rowp[mi][j];
      r += __shfl_xor(r, 1);
      r += __shfl_xor(r, 2);
      r += __shfl_xor(r, 4);
      r += __shfl_xor(r, 8);
      if (fr == 0) {
        atomicAdd(&row_sum[brow + wm * 128 + mi * 16 + fq * 4 + j], r);
      }
    }
  }
  // col sums: reduce across the 4 fq row-groups, 1 atomic per col per wave
  #pragma unroll
  for (int ni = 0; ni < 4; ++ni) {
    float cc = colp[ni];
    cc += __shfl_xor(cc, 16);
    cc += __shfl_xor(cc, 32);
    if (lane < 16) {
      atomicAdd(&col_sum[bcol + wn * 64 + ni * 16 + fr], cc);
    }
  }
}

// ---------- kernel 3: final scalar reduction (block 0 -> rows, block 1 -> cols) ----------
__global__ __launch_bounds__(1024) void fin_kernel(
    const float* __restrict__ row_sum, const float* __restrict__ col_sum,
    const float* __restrict__ log_diag, const float* __restrict__ exp_diag,
    float* __restrict__ out)
{
  const int tid  = threadIdx.x;
  const int lane = tid & 63;
  const int wave = tid >> 6;
  const float* sums = (blockIdx.x == 0) ? row_sum : col_sum;
  float a = 0.0f;
  #pragma unroll
  for (int kk = 0; kk < NN / 1024; ++kk) {
    const int i = tid + kk * 1024;
    a += logf(sums[i] - exp_diag[i]) - log_diag[i];
  }
  #pragma unroll
  for (int off = 1; off < 64; off <<= 1) a += __shfl_xor(a, off);
  __shared__ float r0[16];
  if (lane == 0) r0[wave] = a;
  __syncthreads();
  if (tid == 0) {
    float s = 0.0f;
    #pragma unroll
    for (int w = 0; w < 16; ++w) s += r0[w];
    out[blockIdx.x] = s;
  }
}

extern "C" void kernel_launch(void* const* d_in, const int* in_sizes, int n_in,
                              void* d_out, int out_size, void* d_ws, size_t ws_size,
                              hipStream_t stream) {
  const float* e1 = (const float*)d_in[0];
  const float* e2 = (const float*)d_in[1];
  float* out = (float*)d_out;

  char* ws = (char*)d_ws;
  unsigned short* e1n = (unsigned short*)ws;                            // 8 MB
  unsigned short* e2n = (unsigned short*)(ws + (size_t)NN * DD * 2);    // 8 MB
  float* log_diag = (float*)(ws + (size_t)NN * DD * 4);                 // 16 KB
  float* exp_diag = log_diag + NN;                                      // 16 KB
  float* row_sum  = exp_diag + NN;                                      // 16 KB
  float* col_sum  = row_sum + NN;                                       // 16 KB

  nrm_kernel<<<NN, 256, 0, stream>>>(e1, e2, e1n, e2n, log_diag, exp_diag,
                                     row_sum, col_sum);
  gemm_kernel<<<256, 512, 0, stream>>>(e1n, e2n, row_sum, col_sum);
  fin_kernel<<<2, 1024, 0, stream>>>(row_sum, col_sum, log_diag, exp_diag, out);
}

// Round 6
// 50.052 us; speedup vs baseline: 1.1580x; 1.1580x over previous
//
#include <hip/hip_runtime.h>
#include <hip/hip_bf16.h>
#include <stdint.h>

#define NN 4096
#define DD 1024
// data scaled by 64 per matrix -> products x4096; logits = dot * 10
#define SCL (10.0f / 4096.0f)

typedef float f32x4 __attribute__((ext_vector_type(4)));
typedef long long i64;

__device__ __forceinline__ void gload_lds16(const void* g, void* l) {
  __builtin_amdgcn_global_load_lds(
      (const __attribute__((address_space(1))) void*)g,
      (__attribute__((address_space(3))) void*)l, 16, 0, 0);
}

// ---------- kernel 1: row-L2-normalize -> fp8 e4m3 (x64), exact fp32 diagonal ----------
__global__ __launch_bounds__(256) void nrm_kernel(
    const float* __restrict__ e1, const float* __restrict__ e2,
    uint32_t* __restrict__ e1q, uint32_t* __restrict__ e2q,
    float* __restrict__ log_diag, float* __restrict__ exp_diag,
    float* __restrict__ row_sum, float* __restrict__ col_sum)
{
  const int row  = blockIdx.x;
  const int tid  = threadIdx.x;
  const int lane = tid & 63;
  const int wave = tid >> 6;
  const int64_t base = (int64_t)row * DD;

  const float4 v1 = *reinterpret_cast<const float4*>(e1 + base + tid * 4);
  const float4 v2 = *reinterpret_cast<const float4*>(e2 + base + tid * 4);

  float ss1 = v1.x*v1.x + v1.y*v1.y + v1.z*v1.z + v1.w*v1.w;
  float ss2 = v2.x*v2.x + v2.y*v2.y + v2.z*v2.z + v2.w*v2.w;
  float d12 = v1.x*v2.x + v1.y*v2.y + v1.z*v2.z + v1.w*v2.w;

  #pragma unroll
  for (int off = 1; off < 64; off <<= 1) {
    ss1 += __shfl_xor(ss1, off);
    ss2 += __shfl_xor(ss2, off);
    d12 += __shfl_xor(d12, off);
  }

  __shared__ float red[3][4];
  if (lane == 0) { red[0][wave] = ss1; red[1][wave] = ss2; red[2][wave] = d12; }
  __syncthreads();
  ss1 = red[0][0] + red[0][1] + red[0][2] + red[0][3];
  ss2 = red[1][0] + red[1][1] + red[1][2] + red[1][3];
  d12 = red[2][0] + red[2][1] + red[2][2] + red[2][3];

  const float inv1 = 1.0f / fmaxf(sqrtf(ss1), 1e-12f);
  const float inv2 = 1.0f / fmaxf(sqrtf(ss2), 1e-12f);

  if (tid == 0) {
    const float ld = d12 * inv1 * inv2 * 10.0f;
    log_diag[row] = ld;
    exp_diag[row] = __expf(ld);
    row_sum[row] = 0.0f;
    col_sum[row] = 0.0f;
  }

  const float s1 = inv1 * 64.0f;
  const float s2 = inv2 * 64.0f;
  int u1 = __builtin_amdgcn_cvt_pk_fp8_f32(v1.x * s1, v1.y * s1, 0, false);
  u1     = __builtin_amdgcn_cvt_pk_fp8_f32(v1.z * s1, v1.w * s1, u1, true);
  int u2 = __builtin_amdgcn_cvt_pk_fp8_f32(v2.x * s2, v2.y * s2, 0, false);
  u2     = __builtin_amdgcn_cvt_pk_fp8_f32(v2.z * s2, v2.w * s2, u2, true);
  e1q[row * (DD / 4) + tid] = (uint32_t)u1;
  e2q[row * (DD / 4) + tid] = (uint32_t)u2;
}

// ---------- kernel 2: fused fp8 GEMM 256x128 tile, 2 blocks/CU ----------
// 8 waves (4M x 2N), wave tile 64x64, BK=64, mfma_f32_16x16x32_fp8_fp8.
// LDS 48 KiB (dbuf [2][256|128][64] fp8). One vmcnt(0)+barrier per K-tile;
// staging for tile t issued one full tile earlier -> vmcnt(0) == counted.
// 8B XOR swizzle phys8 = log8 ^ (((row>>1)&3)<<1): write side = 16B-chunk
// XOR (linear gload dest, pre-swizzled source), read side 2-way max (free).
__global__ __launch_bounds__(512, 4) void gemm_kernel(
    const uint8_t* __restrict__ A,   // e1q [NN][DD] fp8 bits (x64)
    const uint8_t* __restrict__ B,   // e2q [NN][DD] fp8 bits (x64)
    float* __restrict__ row_sum, float* __restrict__ col_sum)
{
  __shared__ __align__(16) uint8_t lds_a[2][256][64];   // 32 KiB
  __shared__ __align__(16) uint8_t lds_b[2][128][64];   // 16 KiB

  const int tid  = threadIdx.x;
  const int lane = tid & 63;
  const int wave = tid >> 6;          // 0..7
  const int wm = wave >> 1;           // 0..3 : rows [wm*64, +64)
  const int wn = wave & 1;            // 0..1 : cols [wn*64, +64)

  // XCD swizzle: grid 16x32 tiles; each XCD owns a 4x16 rectangle (3 MB < 4 MB L2)
  const int bid = blockIdx.x;
  const int xcd = bid & 7;
  const int k   = bid >> 3;           // 0..63
  const int brow = ((xcd >> 1) * 4 + (k >> 4)) * 256;
  const int bcol = ((xcd & 1) * 16 + (k & 15)) * 128;

  const int fr = lane & 15;
  const int fq = lane >> 4;
  const int y  = ((fr >> 1) & 3) << 1;          // row-derived XOR (even -> no 8B swap)
  const int o0 = ((fq ^ y) * 8);                // kh0 byte offset; kh1 = o0 ^ 32

  // staging: lane l writes 16B chunk (l&3) of row (l>>2); source chunk pre-swizzled
  const int s_chunk = ((lane & 3) ^ ((lane >> 3) & 3)) * 16;
  const uint8_t* a_src0 = A + (int64_t)(brow + wave * 32 + (lane >> 2)) * DD + s_chunk;
  const uint8_t* a_src1 = a_src0 + 16 * DD;
  const uint8_t* b_src  = B + (int64_t)(bcol + wave * 16 + (lane >> 2)) * DD + s_chunk;

  f32x4 acc[4][4] = {};

#define STAGE(n, kc)                                          \
  gload_lds16(a_src0 + (kc), &lds_a[n][wave * 32][0]);        \
  gload_lds16(a_src1 + (kc), &lds_a[n][wave * 32 + 16][0]);   \
  gload_lds16(b_src  + (kc), &lds_b[n][wave * 16][0]);

#define TILE(c, PF, KC)                                                        \
  {                                                                            \
    asm volatile("s_waitcnt vmcnt(0)" ::: "memory");                           \
    __builtin_amdgcn_s_barrier();                                              \
    i64 a0[4], b0[4], a1[4], b1[4];                                            \
    _Pragma("unroll")                                                          \
    for (int i = 0; i < 4; ++i)                                                \
      a0[i] = *reinterpret_cast<const i64*>(&lds_a[c][wm*64 + i*16 + fr][o0]); \
    _Pragma("unroll")                                                          \
    for (int j = 0; j < 4; ++j)                                                \
      b0[j] = *reinterpret_cast<const i64*>(&lds_b[c][wn*64 + j*16 + fr][o0]); \
    _Pragma("unroll")                                                          \
    for (int i = 0; i < 4; ++i)                                                \
      a1[i] = *reinterpret_cast<const i64*>(                                   \
          &lds_a[c][wm*64 + i*16 + fr][o0 ^ 32]);                              \
    _Pragma("unroll")                                                          \
    for (int j = 0; j < 4; ++j)                                                \
      b1[j] = *reinterpret_cast<const i64*>(                                   \
          &lds_b[c][wn*64 + j*16 + fr][o0 ^ 32]);                              \
    if (PF) { STAGE((c) ^ 1, KC) }                                             \
    __builtin_amdgcn_s_setprio(1);                                             \
    _Pragma("unroll")                                                          \
    for (int i = 0; i < 4; ++i) {                                              \
      _Pragma("unroll")                                                        \
      for (int j = 0; j < 4; ++j)                                              \
        acc[i][j] = __builtin_amdgcn_mfma_f32_16x16x32_fp8_fp8(                \
            a0[i], b0[j], acc[i][j], 0, 0, 0);                                 \
    }                                                                          \
    _Pragma("unroll")                                                          \
    for (int i = 0; i < 4; ++i) {                                              \
      _Pragma("unroll")                                                        \
      for (int j = 0; j < 4; ++j)                                              \
        acc[i][j] = __builtin_amdgcn_mfma_f32_16x16x32_fp8_fp8(                \
            a1[i], b1[j], acc[i][j], 0, 0, 0);                                 \
    }                                                                          \
    __builtin_amdgcn_s_setprio(0);                                             \
  }

  // prologue: stage tile 0 into slot 0
  STAGE(0, 0)

  #pragma unroll 2
  for (int t = 0; t < DD / 64; ++t) {
    TILE(t & 1, t < DD / 64 - 1, (t + 1) * 64)
  }
#undef TILE
#undef STAGE

  // ---- fused epilogue: v = exp(SCL*acc); row & col partial sums ----
  // C/D layout: col = fr, row = fq*4 + j (within each 16x16 fragment)
  float rowp[4][4];
  float colp[4];
  #pragma unroll
  for (int mi = 0; mi < 4; ++mi)
    #pragma unroll
    for (int j = 0; j < 4; ++j) rowp[mi][j] = 0.0f;
  #pragma unroll
  for (int ni = 0; ni < 4; ++ni) colp[ni] = 0.0f;

  #pragma unroll
  for (int mi = 0; mi < 4; ++mi) {
    #pragma unroll
    for (int ni = 0; ni < 4; ++ni) {
      #pragma unroll
      for (int j = 0; j < 4; ++j) {
        const float v = __expf(acc[mi][ni][j] * SCL);
        rowp[mi][j] += v;
        colp[ni]    += v;
      }
    }
  }

  // row sums: reduce across 16 col-lanes, 1 atomic per row per wave
  #pragma unroll
  for (int mi = 0; mi < 4; ++mi) {
    #pragma unroll
    for (int j = 0; j < 4; ++j) {
      float r = rowp[mi][j];
      r += __shfl_xor(r, 1);
      r += __shfl_xor(r, 2);
      r += __shfl_xor(r, 4);
      r += __shfl_xor(r, 8);
      if (fr == 0) {
        atomicAdd(&row_sum[brow + wm * 64 + mi * 16 + fq * 4 + j], r);
      }
    }
  }
  // col sums: reduce across the 4 fq row-groups, 1 atomic per col per wave
  #pragma unroll
  for (int ni = 0; ni < 4; ++ni) {
    float cc = colp[ni];
    cc += __shfl_xor(cc, 16);
    cc += __shfl_xor(cc, 32);
    if (lane < 16) {
      atomicAdd(&col_sum[bcol + wn * 64 + ni * 16 + fr], cc);
    }
  }
}

// ---------- kernel 3: final scalar reduction (block 0 -> rows, block 1 -> cols) ----------
__global__ __launch_bounds__(1024) void fin_kernel(
    const float* __restrict__ row_sum, const float* __restrict__ col_sum,
    const float* __restrict__ log_diag, const float* __restrict__ exp_diag,
    float* __restrict__ out)
{
  const int tid  = threadIdx.x;
  const int lane = tid & 63;
  const int wave = tid >> 6;
  const float* sums = (blockIdx.x == 0) ? row_sum : col_sum;
  float a = 0.0f;
  #pragma unroll
  for (int kk = 0; kk < NN / 1024; ++kk) {
    const int i = tid + kk * 1024;
    a += logf(sums[i] - exp_diag[i]) - log_diag[i];
  }
  #pragma unroll
  for (int off = 1; off < 64; off <<= 1) a += __shfl_xor(a, off);
  __shared__ float r0[16];
  if (lane == 0) r0[wave] = a;
  __syncthreads();
  if (tid == 0) {
    float s = 0.0f;
    #pragma unroll
    for (int w = 0; w < 16; ++w) s += r0[w];
    out[blockIdx.x] = s;
  }
}

extern "C" void kernel_launch(void* const* d_in, const int* in_sizes, int n_in,
                              void* d_out, int out_size, void* d_ws, size_t ws_size,
                              hipStream_t stream) {
  const float* e1 = (const float*)d_in[0];
  const float* e2 = (const float*)d_in[1];
  float* out = (float*)d_out;

  char* ws = (char*)d_ws;
  uint32_t* e1q = (uint32_t*)ws;                                 // 4 MB (fp8)
  uint32_t* e2q = (uint32_t*)(ws + (size_t)NN * DD);             // 4 MB (fp8)
  float* log_diag = (float*)(ws + (size_t)NN * DD * 2);          // 16 KB
  float* exp_diag = log_diag + NN;                               // 16 KB
  float* row_sum  = exp_diag + NN;                               // 16 KB
  float* col_sum  = row_sum + NN;                                // 16 KB

  nrm_kernel<<<NN, 256, 0, stream>>>(e1, e2, e1q, e2q, log_diag, exp_diag,
                                     row_sum, col_sum);
  gemm_kernel<<<512, 512, 0, stream>>>((const uint8_t*)e1q, (const uint8_t*)e2q,
                                       row_sum, col_sum);
  fin_kernel<<<2, 1024, 0, stream>>>(row_sum, col_sum, log_diag, exp_diag, out);
}